// Round 5
// baseline (153.775 us; speedup 1.0000x reference)
//
#include <hip/hip_runtime.h>
#include <hip/hip_bf16.h>

// SE(3)-equivariant layer, MI355X / gfx950 — round 5.
// r4 post-mortem: scattered partial-line prep writes (+58MB RMW/evictions) and
// 4-barrier t-split waves regressed. r5 = r3 dataflow with: (1) A-frags read
// directly from global h_bf (no hl LDS, -32KB), (2) un-paired paths so W2
// slice = 32KB -> edge_ad 51KB LDS @ 3 blk/CU, edge_bc 79.8KB @ 2 blk/CU,
// (3) sorted-order prep (coalesced writes), X1 transposed per tile for
// conflict-free broadcast reads, (4) 2 barriers/tile, dedicated summand.

typedef __attribute__((ext_vector_type(8))) short bf16x8;
typedef __attribute__((ext_vector_type(8))) unsigned short u16x8;
typedef __attribute__((ext_vector_type(4))) float f32x4;

#define NN 10000
#define NE 160000

__device__ __forceinline__ float sus_f(float t) { return t > 0.0f ? __expf(-1.0f / t) : 0.0f; }
__device__ __forceinline__ unsigned int f2bf(float f) {
    unsigned int u = __float_as_uint(f);
    u += 0x7FFFu + ((u >> 16) & 1u);
    return u >> 16;
}
__device__ __forceinline__ float bf2f(unsigned short v) { return __uint_as_float(((unsigned int)v) << 16); }
__device__ __forceinline__ float bflo(unsigned int v) { return __uint_as_float(v << 16); }
__device__ __forceinline__ float bfhi(unsigned int v) { return __uint_as_float(v & 0xFFFF0000u); }
__device__ __forceinline__ float bfe(u16x8 v, int i) { return __uint_as_float(((unsigned int)v[i]) << 16); }

#define GL16(g, l) __builtin_amdgcn_global_load_lds( \
    (const __attribute__((address_space(1))) void*)(g), \
    (__attribute__((address_space(3))) void*)(l), 16, 0, 0)

__device__ __forceinline__ void stageN(const void* g, void* l, int bytes, int tid, int nthr) {
    const char* gc = (const char*)g;
    char* lc = (char*)l;
    const int units = bytes >> 4;
    for (int u = tid; u < units; u += nthr) GL16(gc + ((long)u << 4), lc + (u << 4));
}

// ---------------- hist + W2->bf16 conversion ----------------
__global__ void hist_k(const int* __restrict__ dst, int* __restrict__ hist,
                       const float* __restrict__ w2, char* __restrict__ w2bf) {
    if (blockIdx.x < 625) {
        const int e = blockIdx.x * 256 + threadIdx.x;
        if (e < NE) atomicAdd(&hist[dst[e]], 1);
    } else {
        // W2 -> bf16, transposed + swizzled: row R (out col), chunk j holds k=8j..8j+7
        const int idx = (blockIdx.x - 625) * 256 + threadIdx.x;  // 0..8191
        const int j = idx >> 10, R = idx & 1023;
        unsigned int pk[4];
        #pragma unroll
        for (int p = 0; p < 4; ++p) {
            const unsigned int lo = f2bf(w2[(size_t)(8 * j + 2 * p) * 1024 + R]);
            const unsigned int hi = f2bf(w2[(size_t)(8 * j + 2 * p + 1) * 1024 + R]);
            pk[p] = lo | (hi << 16);
        }
        uint4 v; v.x = pk[0]; v.y = pk[1]; v.z = pk[2]; v.w = pk[3];
        *(uint4*)(w2bf + R * 128 + ((j ^ (R & 7)) << 4)) = v;
    }
}

__global__ __launch_bounds__(1024) void scan_k(const int* __restrict__ hist,
                                               int* __restrict__ offsets) {
    __shared__ int hl[NN];
    __shared__ int wsum[16];
    const int tid = threadIdx.x;
    for (int i = tid; i < NN; i += 1024) hl[i] = hist[i];
    __syncthreads();
    const int base = tid * 10;
    int loc[10]; int s = 0;
    #pragma unroll
    for (int i = 0; i < 10; ++i) { loc[i] = s; const int b = base + i; s += (b < NN) ? hl[b] : 0; }
    int v = s;
    const int lane = tid & 63, wv = tid >> 6;
    #pragma unroll
    for (int d = 1; d < 64; d <<= 1) { int t2 = __shfl_up(v, d); if (lane >= d) v += t2; }
    if (lane == 63) wsum[wv] = v;
    __syncthreads();
    if (tid < 64) {
        int w = (tid < 16) ? wsum[tid] : 0;
        #pragma unroll
        for (int d = 1; d < 16; d <<= 1) { int t2 = __shfl_up(w, d); if (tid >= d) w += t2; }
        if (tid < 16) wsum[tid] = w;
    }
    __syncthreads();
    const int wexc = (wv == 0) ? 0 : wsum[wv - 1];
    const int texc = wexc + v - s;
    #pragma unroll
    for (int i = 0; i < 10; ++i) { const int b = base + i; if (b < NN) offsets[b] = texc + loc[i]; }
    if (tid == 1023) offsets[NN] = texc + s;
}

__global__ void scatter_k(const int* __restrict__ dst, const int* __restrict__ offsets,
                          int* __restrict__ cursor, int* __restrict__ perm,
                          int* __restrict__ dsts) {
    const int e = blockIdx.x * 256 + threadIdx.x;
    if (e < NE) {
        const int d = dst[e];
        const int pos = offsets[d] + atomicAdd(&cursor[d], 1);
        perm[pos] = e;
        dsts[pos] = d;
    }
}

// ---------------- prep: sorted order, coalesced writes ----------------
// block b = sorted tile b (128 positions).
__global__ __launch_bounds__(256, 4) void prep_k(
    const float* __restrict__ x, const float* __restrict__ edge_vec,
    const float* __restrict__ w1, const int* __restrict__ src,
    const int* __restrict__ perm,
    char* __restrict__ h_bf, char* __restrict__ X0g, char* __restrict__ Zg,
    char* __restrict__ X1g, float* __restrict__ Y1g)
{
    __shared__ float embl[128][10];
    __shared__ float y1l[128][4];
    __shared__ int srcl[128];
    __shared__ float w1l[640];
    const int tid = threadIdx.x;
    const long e0 = (long)blockIdx.x * 128;

    for (int i = tid; i < 640; i += 256) w1l[i] = w1[i];
    if (tid < 128) {
        const int e = tid;
        const int eid = perm[e0 + e];
        const float vx = edge_vec[eid * 3 + 0];
        const float vy = edge_vec[eid * 3 + 1];
        const float vz = edge_vec[eid * 3 + 2];
        const float r = sqrtf(vx * vx + vy * vy + vz * vz);
        const float sc = 1.7320508075688772f / r;
        y1l[e][0] = vx * sc; y1l[e][1] = vy * sc; y1l[e][2] = vz * sc; y1l[e][3] = 0.f;
        *(float4*)&Y1g[(e0 + e) * 4] = make_float4(vx * sc, vy * sc, vz * sc, 0.f);
        srcl[e] = src[eid];
        const float C0 = 1.14136f * __expf(2.0f) * 3.1622776601683795f; // * sqrt(10)
        #pragma unroll
        for (int i = 0; i < 10; ++i) {
            const float diff = r * (11.0f / 4.5f) - (float)(i + 1);
            embl[e][i] = C0 * sus_f(diff + 1.0f) * sus_f(1.0f - diff);
        }
    }
    __syncthreads();
    // h = sqrt(2/10)*relu(emb@W1) -> bf16, LINEAR chunks (consumed from global)
    for (int idx = tid; idx < 1024; idx += 256) {
        const int e = idx >> 3, j = idx & 7;
        float acc[8];
        #pragma unroll
        for (int jj = 0; jj < 8; ++jj) acc[jj] = 0.0f;
        #pragma unroll
        for (int i = 0; i < 10; ++i) {
            const float ei = embl[e][i];
            #pragma unroll
            for (int jj = 0; jj < 8; ++jj) acc[jj] += ei * w1l[i * 64 + j * 8 + jj];
        }
        unsigned int pk[4];
        #pragma unroll
        for (int p = 0; p < 4; ++p) {
            const unsigned int lo = f2bf(fmaxf(acc[2 * p],     0.0f) * 0.4472135954999579f);
            const unsigned int hi = f2bf(fmaxf(acc[2 * p + 1], 0.0f) * 0.4472135954999579f);
            pk[p] = lo | (hi << 16);
        }
        uint4 v; v.x = pk[0]; v.y = pk[1]; v.z = pk[2]; v.w = pk[3];
        *(uint4*)(h_bf + (e0 + e) * 128 + (j << 4)) = v;
    }
    // X0 bf16 [16] -> 32B rows
    for (int idx = tid; idx < 1024; idx += 256) {
        const int e = idx >> 3, p = idx & 7;
        const int s = srcl[e];
        const float2 ab = *(const float2*)&x[(size_t)s * 64 + 2 * p];
        *(unsigned int*)(X0g + (e0 + e) * 32 + p * 4) = f2bf(ab.x) | (f2bf(ab.y) << 16);
    }
    // Z bf16 [16] -> 32B rows: z[u] = x1[u].y1
    for (int idx = tid; idx < 1024; idx += 256) {
        const int e = idx >> 3, p = idx & 7;
        const int s = srcl[e];
        const float* xp = x + (size_t)s * 64 + 16 + 6 * p;
        const float z0 = xp[0] * y1l[e][0] + xp[1] * y1l[e][1] + xp[2] * y1l[e][2];
        const float z1 = xp[3] * y1l[e][0] + xp[4] * y1l[e][1] + xp[5] * y1l[e][2];
        *(unsigned int*)(Zg + (e0 + e) * 32 + p * 4) = f2bf(z0) | (f2bf(z1) << 16);
    }
    // X1 bf16, TRANSPOSED per tile: [t][el] 8B slots -> conflict-free broadcast reads
    for (int idx = tid; idx < 2048; idx += 256) {
        const int e = idx >> 4, u = idx & 15;
        const int s = srcl[e];
        const float* xp = x + (size_t)s * 64 + 16 + 3 * u;
        uint2 v;
        v.x = f2bf(xp[0]) | (f2bf(xp[1]) << 16);
        v.y = f2bf(xp[2]);
        *(uint2*)(X1g + (size_t)blockIdx.x * 16384 + ((u << 7) + e) * 8) = v;
    }
}

// ---------------- edge kernel: paths A (y=0) and D (y=1) ----------------
// LDS: w2 32768 | feats[2][4608] (X0/Z 4096 + dst 512) | summ [16][132] f32
__global__ __launch_bounds__(512, 6) void edge_ad(
    const char* __restrict__ w2bf, const char* __restrict__ h_bf,
    const char* __restrict__ X0g, const char* __restrict__ Zg,
    const int* __restrict__ dsts, float* __restrict__ out)
{
    __shared__ __align__(16) char w2lds[32768];
    __shared__ __align__(16) char feats[2][4608];
    __shared__ float summ[16 * 132];
    __shared__ int segst[2][66];
    __shared__ int nseg[2];

    const int tid = threadIdx.x, lane = tid & 63, wv = tid >> 6;
    const int lm = lane & 15, q = lane >> 4, erow = wv << 4;
    const int isD = blockIdx.y;
    const char* featg = isD ? Zg : X0g;
    const int tb = blockIdx.x;                 // 0..249
    const int s0 = (q ^ (lm & 7)) << 4, s1 = s0 ^ 64;
    const float S = 0.17677669529663687f * 0.125f * 0.0625f;
    const float scl = isD ? S * 0.5773502691896258f : S;

    stageN(w2bf + (isD ? 3 : 0) * 32768, w2lds, 32768, tid, 512);
    {
        const long e0 = (long)tb * 5 * 128;
        stageN(featg + e0 * 32, feats[0], 4096, tid, 512);
        stageN((const char*)(dsts + e0), feats[0] + 4096, 512, tid, 512);
    }
    __syncthreads();

    for (int tt = 0; tt < 5; ++tt) {
        char* fb = feats[tt & 1];
        const long e0 = ((long)tb * 5 + tt) * 128;
        if (tt < 4) {
            char* nb = feats[(tt & 1) ^ 1];
            stageN(featg + (e0 + 128) * 32, nb, 4096, tid, 512);
            stageN((const char*)(dsts + e0 + 128), nb + 4096, 512, tid, 512);
        }
        const int arow = erow + lm;
        const bf16x8 a0 = *(const bf16x8*)(h_bf + (e0 + arow) * 128 + q * 16);
        const bf16x8 a1 = *(const bf16x8*)(h_bf + (e0 + arow) * 128 + 64 + q * 16);
        u16x8 flo[4], fhi[4];
        #pragma unroll
        for (int r = 0; r < 4; ++r) {
            const int el = erow + 4 * q + r;
            flo[r] = *(const u16x8*)(fb + el * 32);
            fhi[r] = *(const u16x8*)(fb + el * 32 + 16);
        }
        float ac[4] = {0.f, 0.f, 0.f, 0.f};
        #pragma unroll
        for (int t = 0; t < 16; ++t) {
            const int rowb = (t * 16 + lm) << 7;
            const bf16x8 b0 = *(const bf16x8*)(w2lds + rowb + s0);
            const bf16x8 b1 = *(const bf16x8*)(w2lds + rowb + s1);
            f32x4 w = {0.f, 0.f, 0.f, 0.f};
            w = __builtin_amdgcn_mfma_f32_16x16x32_bf16(a0, b0, w, 0, 0, 0);
            w = __builtin_amdgcn_mfma_f32_16x16x32_bf16(a1, b1, w, 0, 0, 0);
            #pragma unroll
            for (int r = 0; r < 4; ++r)
                ac[r] += w[r] * (t < 8 ? bfe(flo[r], t) : bfe(fhi[r], t - 8));
        }
        const int* dstl = (const int*)(fb + 4096);
        #pragma unroll
        for (int r = 0; r < 4; ++r) {
            const int el = erow + 4 * q + r;
            summ[lm * 132 + el] = scl * ac[r];
        }
        if (wv < 2) {
            const int base = wv << 6;
            const int d = dstl[base + lane];
            const bool flag = (lane == 0) || (d != dstl[base + lane - 1]);
            const unsigned long long m = __ballot(flag);
            const int sid = (lane == 0) ? 0 : __popcll(m & ((1ull << lane) - 1ull));
            if (flag) segst[wv][sid] = base + lane;
            if (lane == 63) { const int ns = __popcll(m); nseg[wv] = ns; segst[wv][ns] = base + 64; }
        }
        __syncthreads();  // B1: summand/segments visible; next-tile stage drained
        const int nsa = nseg[0], nsb = nseg[1];
        const int total = (nsa + nsb) << 4;
        for (int i = tid; i < total; i += 512) {
            const int sg = i >> 4, c = i & 15;
            const int hh = (sg >= nsa) ? 1 : 0;
            const int sl = hh ? sg - nsa : sg;
            const int eb = segst[hh][sl], ee = segst[hh][sl + 1];
            float s = 0.f;
            for (int e = eb; e < ee; ++e) s += summ[c * 132 + e];
            atomicAdd(&out[(size_t)dstl[eb] * 64 + c], s);
        }
        __syncthreads();  // B2: reduce done
    }
}

// ---------------- edge kernel: paths B (y=0) and C (y=1) ----------------
// LDS: w2 32768 | feats[2][16896] (B: X0 4096 + Y1 2048 + dst@6144;
//                                  C: X1 16384 + dst@16384) | summ [48][132] u16
#define FEATSZ 16896

__global__ __launch_bounds__(512, 4) void edge_bc(
    const char* __restrict__ w2bf, const char* __restrict__ h_bf,
    const char* __restrict__ X0g, const char* __restrict__ X1g,
    const float* __restrict__ Y1g, const int* __restrict__ dsts,
    float* __restrict__ out)
{
    __shared__ __align__(16) char w2lds[32768];
    __shared__ __align__(16) char feats[2][FEATSZ];
    __shared__ unsigned short summ[48 * 132];
    __shared__ int segst[2][66];
    __shared__ int nseg[2];

    const int tid = threadIdx.x, lane = tid & 63, wv = tid >> 6;
    const int lm = lane & 15, q = lane >> 4, erow = wv << 4;
    const int isC = blockIdx.y;
    const int tb = blockIdx.x;
    const int s0 = (q ^ (lm & 7)) << 4, s1 = s0 ^ 64;
    const int dstoff = isC ? 16384 : 6144;
    const float S = 0.17677669529663687f * 0.125f * 0.0625f;

    auto stage_tile = [&](char* nb, long e0) {
        if (isC) {
            stageN(X1g + (e0 >> 7) * 16384, nb, 16384, tid, 512);
        } else {
            stageN(X0g + e0 * 32, nb, 4096, tid, 512);
            stageN((const char*)(Y1g + e0 * 4), nb + 4096, 2048, tid, 512);
        }
        stageN((const char*)(dsts + e0), nb + dstoff, 512, tid, 512);
    };

    stageN(w2bf + (isC ? 2 : 1) * 32768, w2lds, 32768, tid, 512);
    stage_tile(feats[0], (long)tb * 5 * 128);
    __syncthreads();

    for (int tt = 0; tt < 5; ++tt) {
        char* fb = feats[tt & 1];
        const long e0 = ((long)tb * 5 + tt) * 128;
        if (tt < 4) stage_tile(feats[(tt & 1) ^ 1], e0 + 128);

        const int arow = erow + lm;
        const bf16x8 a0 = *(const bf16x8*)(h_bf + (e0 + arow) * 128 + q * 16);
        const bf16x8 a1 = *(const bf16x8*)(h_bf + (e0 + arow) * 128 + 64 + q * 16);

        if (isC) {
            float ac1[4] = {0,0,0,0}, ac2[4] = {0,0,0,0}, ac3[4] = {0,0,0,0};
            #pragma unroll
            for (int t = 0; t < 16; ++t) {
                const int rowb = (t * 16 + lm) << 7;
                const bf16x8 b0 = *(const bf16x8*)(w2lds + rowb + s0);
                const bf16x8 b1 = *(const bf16x8*)(w2lds + rowb + s1);
                f32x4 w = {0.f, 0.f, 0.f, 0.f};
                w = __builtin_amdgcn_mfma_f32_16x16x32_bf16(a0, b0, w, 0, 0, 0);
                w = __builtin_amdgcn_mfma_f32_16x16x32_bf16(a1, b1, w, 0, 0, 0);
                #pragma unroll
                for (int r = 0; r < 4; ++r) {
                    const int el = erow + 4 * q + r;
                    const uint2 xv = *(const uint2*)(fb + ((t << 7) + el) * 8);
                    ac1[r] += w[r] * bflo(xv.x);
                    ac2[r] += w[r] * bfhi(xv.x);
                    ac3[r] += w[r] * bflo(xv.y);
                }
            }
            #pragma unroll
            for (int r = 0; r < 4; ++r) {
                const int el = erow + 4 * q + r;
                summ[(3 * lm + 0) * 132 + el] = (unsigned short)f2bf(S * ac1[r]);
                summ[(3 * lm + 1) * 132 + el] = (unsigned short)f2bf(S * ac2[r]);
                summ[(3 * lm + 2) * 132 + el] = (unsigned short)f2bf(S * ac3[r]);
            }
        } else {
            u16x8 flo[4], fhi[4];
            #pragma unroll
            for (int r = 0; r < 4; ++r) {
                const int el = erow + 4 * q + r;
                flo[r] = *(const u16x8*)(fb + el * 32);
                fhi[r] = *(const u16x8*)(fb + el * 32 + 16);
            }
            float ac[4] = {0.f, 0.f, 0.f, 0.f};
            #pragma unroll
            for (int t = 0; t < 16; ++t) {
                const int rowb = (t * 16 + lm) << 7;
                const bf16x8 b0 = *(const bf16x8*)(w2lds + rowb + s0);
                const bf16x8 b1 = *(const bf16x8*)(w2lds + rowb + s1);
                f32x4 w = {0.f, 0.f, 0.f, 0.f};
                w = __builtin_amdgcn_mfma_f32_16x16x32_bf16(a0, b0, w, 0, 0, 0);
                w = __builtin_amdgcn_mfma_f32_16x16x32_bf16(a1, b1, w, 0, 0, 0);
                #pragma unroll
                for (int r = 0; r < 4; ++r)
                    ac[r] += w[r] * (t < 8 ? bfe(flo[r], t) : bfe(fhi[r], t - 8));
            }
            #pragma unroll
            for (int r = 0; r < 4; ++r) {
                const int el = erow + 4 * q + r;
                const float4 y = *(const float4*)(fb + 4096 + el * 16);
                const float b = S * ac[r];
                summ[(3 * lm + 0) * 132 + el] = (unsigned short)f2bf(b * y.x);
                summ[(3 * lm + 1) * 132 + el] = (unsigned short)f2bf(b * y.y);
                summ[(3 * lm + 2) * 132 + el] = (unsigned short)f2bf(b * y.z);
            }
        }
        const int* dstl = (const int*)(fb + dstoff);
        if (wv < 2) {
            const int base = wv << 6;
            const int d = dstl[base + lane];
            const bool flag = (lane == 0) || (d != dstl[base + lane - 1]);
            const unsigned long long m = __ballot(flag);
            const int sid = (lane == 0) ? 0 : __popcll(m & ((1ull << lane) - 1ull));
            if (flag) segst[wv][sid] = base + lane;
            if (lane == 63) { const int ns = __popcll(m); nseg[wv] = ns; segst[wv][ns] = base + 64; }
        }
        __syncthreads();  // B1
        const int nsa = nseg[0], nsb = nseg[1];
        const int total = (nsa + nsb) * 48;
        for (int i = tid; i < total; i += 512) {
            const int sg = i / 48, c = i - sg * 48;
            const int hh = (sg >= nsa) ? 1 : 0;
            const int sl = hh ? sg - nsa : sg;
            const int eb = segst[hh][sl], ee = segst[hh][sl + 1];
            float s = 0.f;
            for (int e = eb; e < ee; ++e) s += bf2f(summ[c * 132 + e]);
            atomicAdd(&out[(size_t)dstl[eb] * 64 + 16 + c], s);
        }
        __syncthreads();  // B2
    }
}

// ---------------- fallback (round-2 path, small-ws) ----------------
#define FBT 64
template<int PATH>
__device__ __forceinline__ void fb_body(
    const float* __restrict__ x, const float* __restrict__ edge_vec,
    const float* __restrict__ w1, const float* __restrict__ w2,
    const int* __restrict__ src, const int* __restrict__ perm,
    const int* __restrict__ dsts, float* __restrict__ out,
    unsigned short (*w2t)[72], float* arena, float (*y1l)[4],
    int* dstl, int* srcl, int* segstart, int* nseg_s)
{
    constexpr int NC    = (PATH == 0 || PATH == 3) ? 16 : 48;
    constexpr int CBASE = (PATH == 0 || PATH == 3) ? 0 : 16;
    const int tid = threadIdx.x;
    float* embl = arena;
    unsigned short* hl = (unsigned short*)(arena + 640);
    float* feats = arena + 2944;
    float* summ  = arena;
    {
        const float* col = w2 + PATH * 256 + tid;
        #pragma unroll
        for (int k = 0; k < 64; k += 2) {
            const unsigned int lo = f2bf(col[(size_t)k * 1024]);
            const unsigned int hi = f2bf(col[(size_t)(k + 1) * 1024]);
            *(unsigned int*)&w2t[tid][k] = lo | (hi << 16);
        }
    }
    const int lane = tid & 63, wv = tid >> 6, lm = lane & 15, q = lane >> 4;
    const int erow = wv * 16;
    const float C0 = 1.14136f * __expf(2.0f) * 3.1622776601683795f;
    const float S  = 0.17677669529663687f * 0.125f * 0.0625f;
    for (int it = 0; it < 2; ++it) {
        const int e0 = (blockIdx.x * 2 + it) * FBT;
        __syncthreads();
        for (int idx = tid; idx < FBT * 10; idx += 256) {
            const int e = idx / 10, i = idx - e * 10;
            const int eid = perm[e0 + e];
            const float vx = edge_vec[eid * 3 + 0], vy = edge_vec[eid * 3 + 1], vz = edge_vec[eid * 3 + 2];
            const float r = sqrtf(vx * vx + vy * vy + vz * vz);
            const float diff = r * (11.0f / 4.5f) - (float)(i + 1);
            embl[e * 10 + i] = C0 * sus_f(diff + 1.0f) * sus_f(1.0f - diff);
            if (i == 0) {
                const float sc = 1.7320508075688772f / r;
                y1l[e][0] = vx * sc; y1l[e][1] = vy * sc; y1l[e][2] = vz * sc;
                dstl[e] = dsts[e0 + e];
                srcl[e] = src[eid];
            }
        }
        __syncthreads();
        for (int idx = tid; idx < FBT * 8; idx += 256) {
            const int e = idx >> 3, j0 = (idx & 7) * 8;
            float acc[8];
            #pragma unroll
            for (int j = 0; j < 8; ++j) acc[j] = 0.0f;
            #pragma unroll
            for (int i = 0; i < 10; ++i) {
                const float ei = embl[e * 10 + i];
                #pragma unroll
                for (int j = 0; j < 8; ++j) acc[j] += ei * w1[i * 64 + j0 + j];
            }
            unsigned int pk[4];
            #pragma unroll
            for (int p = 0; p < 4; ++p) {
                const unsigned int lo = f2bf(fmaxf(acc[2 * p],     0.0f) * 0.4472135954999579f);
                const unsigned int hi = f2bf(fmaxf(acc[2 * p + 1], 0.0f) * 0.4472135954999579f);
                pk[p] = lo | (hi << 16);
            }
            uint4 v; v.x = pk[0]; v.y = pk[1]; v.z = pk[2]; v.w = pk[3];
            *(uint4*)&hl[e * 72 + j0] = v;
        }
        if (PATH == 2) {
            for (int idx = tid; idx < FBT * 48; idx += 256) {
                const int e = idx / 48, c = idx - e * 48;
                feats[e * 48 + c] = x[(size_t)srcl[e] * 64 + 16 + c];
            }
        } else if (PATH == 3) {
            for (int idx = tid; idx < FBT * 16; idx += 256) {
                const int e = idx >> 4, u = idx & 15;
                const float* xs = x + (size_t)srcl[e] * 64 + 16 + u * 3;
                feats[e * 16 + u] = xs[0] * y1l[e][0] + xs[1] * y1l[e][1] + xs[2] * y1l[e][2];
            }
        } else {
            for (int idx = tid; idx < FBT * 16; idx += 256) {
                const int e = idx >> 4, u = idx & 15;
                feats[e * 16 + u] = x[(size_t)srcl[e] * 64 + u];
            }
        }
        __syncthreads();
        const bf16x8 a0 = *(const bf16x8*)&hl[(erow + lm) * 72 + 8 * q];
        const bf16x8 a1 = *(const bf16x8*)&hl[(erow + lm) * 72 + 32 + 8 * q];
        float accO[4] = {0.f,0.f,0.f,0.f}, accC0[4] = {0.f,0.f,0.f,0.f};
        float accC1[4] = {0.f,0.f,0.f,0.f}, accC2[4] = {0.f,0.f,0.f,0.f};
        #pragma unroll 4
        for (int t = 0; t < 16; ++t) {
            const bf16x8 b0 = *(const bf16x8*)&w2t[t * 16 + lm][8 * q];
            const bf16x8 b1 = *(const bf16x8*)&w2t[t * 16 + lm][32 + 8 * q];
            f32x4 wa = {0.f,0.f,0.f,0.f};
            wa = __builtin_amdgcn_mfma_f32_16x16x32_bf16(a0, b0, wa, 0, 0, 0);
            wa = __builtin_amdgcn_mfma_f32_16x16x32_bf16(a1, b1, wa, 0, 0, 0);
            #pragma unroll
            for (int r = 0; r < 4; ++r) {
                const int el = erow + 4 * q + r;
                if (PATH == 2) {
                    accC0[r] += wa[r] * feats[el * 48 + t * 3 + 0];
                    accC1[r] += wa[r] * feats[el * 48 + t * 3 + 1];
                    accC2[r] += wa[r] * feats[el * 48 + t * 3 + 2];
                } else {
                    accO[r] += wa[r] * feats[el * 16 + t];
                }
            }
        }
        __syncthreads();
        #pragma unroll
        for (int r = 0; r < 4; ++r) {
            const int el = erow + 4 * q + r;
            if (PATH == 0) summ[el * 16 + lm] = S * accO[r];
            else if (PATH == 3) summ[el * 16 + lm] = S * 0.5773502691896258f * accO[r];
            else if (PATH == 1) {
                const float tv = S * accO[r];
                summ[el * 48 + lm * 3 + 0] = tv * y1l[el][0];
                summ[el * 48 + lm * 3 + 1] = tv * y1l[el][1];
                summ[el * 48 + lm * 3 + 2] = tv * y1l[el][2];
            } else {
                summ[el * 48 + lm * 3 + 0] = S * accC0[r];
                summ[el * 48 + lm * 3 + 1] = S * accC1[r];
                summ[el * 48 + lm * 3 + 2] = S * accC2[r];
            }
        }
        if (tid < 64) {
            const int d = dstl[tid];
            const bool flag = (tid == 0) || (d != dstl[tid - 1]);
            const unsigned long long m = __ballot(flag);
            const int sid = (tid == 0) ? 0 : __popcll(m & ((1ull << tid) - 1ull));
            if (flag) segstart[sid] = tid;
            if (tid == 63) { const int ns = __popcll(m); *nseg_s = ns; segstart[ns] = 64; }
        }
        __syncthreads();
        const int ns = *nseg_s;
        for (int i = tid; i < ns * NC; i += 256) {
            const int s = i / NC, c = i - s * NC;
            const int eb = segstart[s], ee = segstart[s + 1];
            float sum = 0.0f;
            for (int e = eb; e < ee; ++e) sum += summ[e * NC + c];
            atomicAdd(&out[(size_t)dstl[eb] * 64 + CBASE + c], sum);
        }
    }
}

__global__ __launch_bounds__(256, 2) void fb_edge(
    const float* __restrict__ x, const float* __restrict__ edge_vec,
    const float* __restrict__ w1, const float* __restrict__ w2,
    const int* __restrict__ src, const int* __restrict__ perm,
    const int* __restrict__ dsts, float* __restrict__ out)
{
    __shared__ unsigned short w2t[256][72];
    __shared__ float arena[6016];
    __shared__ float y1l[FBT][4];
    __shared__ int dstl[FBT];
    __shared__ int srcl[FBT];
    __shared__ int segstart[FBT + 1];
    __shared__ int nseg_s;
    switch (blockIdx.y) {
        case 0:  fb_body<0>(x, edge_vec, w1, w2, src, perm, dsts, out, w2t, arena, y1l, dstl, srcl, segstart, &nseg_s); break;
        case 1:  fb_body<1>(x, edge_vec, w1, w2, src, perm, dsts, out, w2t, arena, y1l, dstl, srcl, segstart, &nseg_s); break;
        case 2:  fb_body<2>(x, edge_vec, w1, w2, src, perm, dsts, out, w2t, arena, y1l, dstl, srcl, segstart, &nseg_s); break;
        default: fb_body<3>(x, edge_vec, w1, w2, src, perm, dsts, out, w2t, arena, y1l, dstl, srcl, segstart, &nseg_s); break;
    }
}

// ---------------- host ----------------
extern "C" void kernel_launch(void* const* d_in, const int* in_sizes, int n_in,
                              void* d_out, int out_size, void* d_ws, size_t ws_size,
                              hipStream_t stream) {
    const float* x        = (const float*)d_in[0];
    const float* edge_vec = (const float*)d_in[1];
    const float* w1       = (const float*)d_in[2];
    const float* w2       = (const float*)d_in[3];
    const int*   src      = (const int*)d_in[4];
    const int*   dst      = (const int*)d_in[5];
    float* out = (float*)d_out;

    char* ws = (char*)d_ws;
    size_t off = 0;
    auto alloc = [&](size_t n) -> char* {
        off = (off + 255) & ~(size_t)255;
        char* p = ws + off; off += n; return p;
    };
    int* hist    = (int*)alloc(40000);
    int* cursor  = (int*)alloc(40000);
    int* offsets = (int*)alloc(40004);
    int* perm    = (int*)alloc(640000);
    int* dsts    = (int*)alloc(640000);
    char* w2bf   = alloc(131072);
    char* h_bf   = alloc((size_t)NE * 128);
    char* X0g    = alloc((size_t)NE * 32);
    char* Zg     = alloc((size_t)NE * 32);
    char* X1g    = alloc((size_t)NE * 128);
    float* Y1g   = (float*)alloc((size_t)NE * 16);
    const bool big = (off <= ws_size);

    hipMemsetAsync(d_out, 0, (size_t)out_size * sizeof(float), stream);
    hipMemsetAsync(d_ws, 0, 81408, stream);  // hist + cursor

    if (big) {
        hipLaunchKernelGGL(hist_k, dim3(657), dim3(256), 0, stream, dst, hist, w2, w2bf);
        hipLaunchKernelGGL(scan_k, dim3(1), dim3(1024), 0, stream, hist, offsets);
        hipLaunchKernelGGL(scatter_k, dim3(625), dim3(256), 0, stream, dst, offsets, cursor, perm, dsts);
        hipLaunchKernelGGL(prep_k, dim3(1250), dim3(256), 0, stream,
                           x, edge_vec, w1, src, perm, h_bf, X0g, Zg, X1g, Y1g);
        hipLaunchKernelGGL(edge_bc, dim3(250, 2), dim3(512), 0, stream,
                           w2bf, h_bf, X0g, X1g, Y1g, dsts, out);
        hipLaunchKernelGGL(edge_ad, dim3(250, 2), dim3(512), 0, stream,
                           w2bf, h_bf, X0g, Zg, dsts, out);
    } else {
        hipLaunchKernelGGL(hist_k, dim3(625), dim3(256), 0, stream, dst, hist, w2, w2bf);
        hipLaunchKernelGGL(scan_k, dim3(1), dim3(1024), 0, stream, hist, offsets);
        hipLaunchKernelGGL(scatter_k, dim3(625), dim3(256), 0, stream, dst, offsets, cursor, perm, dsts);
        hipLaunchKernelGGL(fb_edge, dim3(1250, 4), dim3(256), 0, stream,
                           x, edge_vec, w1, w2, src, perm, dsts, out);
    }
}

// Round 8
// 127.461 us; speedup vs baseline: 1.2064x; 1.2064x over previous
//
#include <hip/hip_runtime.h>
#include <hip/hip_bf16.h>

// SE(3)-equivariant layer, MI355X / gfx950 — round 8.
// r6/r7's in-kernel x-gather failed correctness twice (cause not localized);
// reverting to proven components only: r3's paired edge kernel ({A,D},{B,C})
// rebuilt with r5-proven pieces — a0/a1 from global h_bf (no hl LDS), bf16
// X0/Z 32B-rows, bf16 tile-transposed X1, stageN staging, r5 summand/reduce.
// LDS 125KB (1 blk/CU) but ~half of r3's staged bytes.

typedef __attribute__((ext_vector_type(8))) short bf16x8;
typedef __attribute__((ext_vector_type(8))) unsigned short u16x8;
typedef __attribute__((ext_vector_type(4))) float f32x4;

#define NN 10000
#define NE 160000

__device__ __forceinline__ float sus_f(float t) { return t > 0.0f ? __expf(-1.0f / t) : 0.0f; }
__device__ __forceinline__ unsigned int f2bf(float f) {
    unsigned int u = __float_as_uint(f);
    u += 0x7FFFu + ((u >> 16) & 1u);
    return u >> 16;
}
__device__ __forceinline__ float bf2f(unsigned short v) { return __uint_as_float(((unsigned int)v) << 16); }
__device__ __forceinline__ float bflo(unsigned int v) { return __uint_as_float(v << 16); }
__device__ __forceinline__ float bfhi(unsigned int v) { return __uint_as_float(v & 0xFFFF0000u); }
__device__ __forceinline__ float bfe(u16x8 v, int i) { return __uint_as_float(((unsigned int)v[i]) << 16); }

#define GL16(g, l) __builtin_amdgcn_global_load_lds( \
    (const __attribute__((address_space(1))) void*)(g), \
    (__attribute__((address_space(3))) void*)(l), 16, 0, 0)

__device__ __forceinline__ void stageN(const void* g, void* l, int bytes, int tid, int nthr) {
    const char* gc = (const char*)g;
    char* lc = (char*)l;
    const int units = bytes >> 4;
    for (int u = tid; u < units; u += nthr) GL16(gc + ((long)u << 4), lc + (u << 4));
}

// ---------------- hist + W2->bf16 conversion ----------------
__global__ void hist_k(const int* __restrict__ dst, int* __restrict__ hist,
                       const float* __restrict__ w2, char* __restrict__ w2bf) {
    if (blockIdx.x < 625) {
        const int e = blockIdx.x * 256 + threadIdx.x;
        if (e < NE) atomicAdd(&hist[dst[e]], 1);
    } else {
        // W2 -> bf16, transposed + swizzled: row R (out col), chunk j holds k=8j..8j+7
        const int idx = (blockIdx.x - 625) * 256 + threadIdx.x;  // 0..8191
        const int j = idx >> 10, R = idx & 1023;
        unsigned int pk[4];
        #pragma unroll
        for (int p = 0; p < 4; ++p) {
            const unsigned int lo = f2bf(w2[(size_t)(8 * j + 2 * p) * 1024 + R]);
            const unsigned int hi = f2bf(w2[(size_t)(8 * j + 2 * p + 1) * 1024 + R]);
            pk[p] = lo | (hi << 16);
        }
        uint4 v; v.x = pk[0]; v.y = pk[1]; v.z = pk[2]; v.w = pk[3];
        *(uint4*)(w2bf + R * 128 + ((j ^ (R & 7)) << 4)) = v;
    }
}

__global__ __launch_bounds__(1024) void scan_k(const int* __restrict__ hist,
                                               int* __restrict__ offsets) {
    __shared__ int hl[NN];
    __shared__ int wsum[16];
    const int tid = threadIdx.x;
    for (int i = tid; i < NN; i += 1024) hl[i] = hist[i];
    __syncthreads();
    const int base = tid * 10;
    int loc[10]; int s = 0;
    #pragma unroll
    for (int i = 0; i < 10; ++i) { loc[i] = s; const int b = base + i; s += (b < NN) ? hl[b] : 0; }
    int v = s;
    const int lane = tid & 63, wv = tid >> 6;
    #pragma unroll
    for (int d = 1; d < 64; d <<= 1) { int t2 = __shfl_up(v, d); if (lane >= d) v += t2; }
    if (lane == 63) wsum[wv] = v;
    __syncthreads();
    if (tid < 64) {
        int w = (tid < 16) ? wsum[tid] : 0;
        #pragma unroll
        for (int d = 1; d < 16; d <<= 1) { int t2 = __shfl_up(w, d); if (tid >= d) w += t2; }
        if (tid < 16) wsum[tid] = w;
    }
    __syncthreads();
    const int wexc = (wv == 0) ? 0 : wsum[wv - 1];
    const int texc = wexc + v - s;
    #pragma unroll
    for (int i = 0; i < 10; ++i) { const int b = base + i; if (b < NN) offsets[b] = texc + loc[i]; }
    if (tid == 1023) offsets[NN] = texc + s;
}

__global__ void scatter_k(const int* __restrict__ dst, const int* __restrict__ offsets,
                          int* __restrict__ cursor, int* __restrict__ perm,
                          int* __restrict__ dsts) {
    const int e = blockIdx.x * 256 + threadIdx.x;
    if (e < NE) {
        const int d = dst[e];
        const int pos = offsets[d] + atomicAdd(&cursor[d], 1);
        perm[pos] = e;
        dsts[pos] = d;
    }
}

// ---------------- prep: sorted order, coalesced writes (r5-proven) ----------------
__global__ __launch_bounds__(256, 4) void prep_k(
    const float* __restrict__ x, const float* __restrict__ edge_vec,
    const float* __restrict__ w1, const int* __restrict__ src,
    const int* __restrict__ perm,
    char* __restrict__ h_bf, char* __restrict__ X0g, char* __restrict__ Zg,
    char* __restrict__ X1g, float* __restrict__ Y1g)
{
    __shared__ float embl[128][10];
    __shared__ float y1l[128][4];
    __shared__ int srcl[128];
    __shared__ float w1l[640];
    const int tid = threadIdx.x;
    const long e0 = (long)blockIdx.x * 128;

    for (int i = tid; i < 640; i += 256) w1l[i] = w1[i];
    if (tid < 128) {
        const int e = tid;
        const int eid = perm[e0 + e];
        const float vx = edge_vec[eid * 3 + 0];
        const float vy = edge_vec[eid * 3 + 1];
        const float vz = edge_vec[eid * 3 + 2];
        const float r = sqrtf(vx * vx + vy * vy + vz * vz);
        const float sc = 1.7320508075688772f / r;
        y1l[e][0] = vx * sc; y1l[e][1] = vy * sc; y1l[e][2] = vz * sc; y1l[e][3] = 0.f;
        *(float4*)&Y1g[(e0 + e) * 4] = make_float4(vx * sc, vy * sc, vz * sc, 0.f);
        srcl[e] = src[eid];
        const float C0 = 1.14136f * __expf(2.0f) * 3.1622776601683795f; // * sqrt(10)
        #pragma unroll
        for (int i = 0; i < 10; ++i) {
            const float diff = r * (11.0f / 4.5f) - (float)(i + 1);
            embl[e][i] = C0 * sus_f(diff + 1.0f) * sus_f(1.0f - diff);
        }
    }
    __syncthreads();
    // h = sqrt(2/10)*relu(emb@W1) -> bf16, LINEAR chunks
    for (int idx = tid; idx < 1024; idx += 256) {
        const int e = idx >> 3, j = idx & 7;
        float acc[8];
        #pragma unroll
        for (int jj = 0; jj < 8; ++jj) acc[jj] = 0.0f;
        #pragma unroll
        for (int i = 0; i < 10; ++i) {
            const float ei = embl[e][i];
            #pragma unroll
            for (int jj = 0; jj < 8; ++jj) acc[jj] += ei * w1l[i * 64 + j * 8 + jj];
        }
        unsigned int pk[4];
        #pragma unroll
        for (int p = 0; p < 4; ++p) {
            const unsigned int lo = f2bf(fmaxf(acc[2 * p],     0.0f) * 0.4472135954999579f);
            const unsigned int hi = f2bf(fmaxf(acc[2 * p + 1], 0.0f) * 0.4472135954999579f);
            pk[p] = lo | (hi << 16);
        }
        uint4 v; v.x = pk[0]; v.y = pk[1]; v.z = pk[2]; v.w = pk[3];
        *(uint4*)(h_bf + (e0 + e) * 128 + (j << 4)) = v;
    }
    // X0 bf16 [16] -> 32B rows
    for (int idx = tid; idx < 1024; idx += 256) {
        const int e = idx >> 3, p = idx & 7;
        const int s = srcl[e];
        const float2 ab = *(const float2*)&x[(size_t)s * 64 + 2 * p];
        *(unsigned int*)(X0g + (e0 + e) * 32 + p * 4) = f2bf(ab.x) | (f2bf(ab.y) << 16);
    }
    // Z bf16 [16] -> 32B rows: z[u] = x1[u].y1
    for (int idx = tid; idx < 1024; idx += 256) {
        const int e = idx >> 3, p = idx & 7;
        const int s = srcl[e];
        const float* xp = x + (size_t)s * 64 + 16 + 6 * p;
        const float z0 = xp[0] * y1l[e][0] + xp[1] * y1l[e][1] + xp[2] * y1l[e][2];
        const float z1 = xp[3] * y1l[e][0] + xp[4] * y1l[e][1] + xp[5] * y1l[e][2];
        *(unsigned int*)(Zg + (e0 + e) * 32 + p * 4) = f2bf(z0) | (f2bf(z1) << 16);
    }
    // X1 bf16, TRANSPOSED per tile: [u][e] 8B slots, row stride 1024B
    for (int idx = tid; idx < 2048; idx += 256) {
        const int e = idx >> 4, u = idx & 15;
        const int s = srcl[e];
        const float* xp = x + (size_t)s * 64 + 16 + 3 * u;
        uint2 v;
        v.x = f2bf(xp[0]) | (f2bf(xp[1]) << 16);
        v.y = f2bf(xp[2]);
        *(uint2*)(X1g + (size_t)blockIdx.x * 16384 + ((u << 7) + e) * 8) = v;
    }
}

// ---------------- paired edge kernel: y=0 -> {A,D}, y=1 -> {B,C} ----------------
// buf (per tile): X0 [128][32B] @0 | pair0: Z [128][32B] @4096
//                 pair1: X1T [16][1024B] @4096 + Y1 [128][16B] @20736
//                 dst @22784 (512B)
#define DSTOFF 22784
#define EBUF 23296

__global__ __launch_bounds__(512, 2) void se3_edge(
    const char* __restrict__ w2bf, const char* __restrict__ h_bf,
    const char* __restrict__ X0g, const char* __restrict__ Zg,
    const char* __restrict__ X1g, const float* __restrict__ Y1g,
    const int* __restrict__ dsts, float* __restrict__ out)
{
    __shared__ __align__(16) char w2lds[65536];
    __shared__ __align__(16) char bufs[2][EBUF];
    __shared__ __align__(16) char summb[12672];   // f32[16*132] (pair0) / u16[48*132] (pair1)
    __shared__ int segst[2][66];
    __shared__ int nseg[2];

    const int tid = threadIdx.x, lane = tid & 63, wv = tid >> 6;
    const int lm = lane & 15, q = lane >> 4, erow = wv << 4;
    const int pair = blockIdx.y;
    const int tb = blockIdx.x;                 // 0..249
    const int s0 = (q ^ (lm & 7)) << 4, s1 = s0 ^ 64;
    const float S = 0.17677669529663687f * 0.125f * 0.0625f; // c * (1/8) * (N/E)

    auto stage_tile = [&](char* nb, long e0) {
        stageN(X0g + e0 * 32, nb, 4096, tid, 512);
        if (pair == 0) {
            stageN(Zg + e0 * 32, nb + 4096, 4096, tid, 512);
        } else {
            stageN(X1g + (e0 >> 7) * 16384, nb + 4096, 16384, tid, 512);
            stageN((const char*)(Y1g + e0 * 4), nb + 20736, 2048, tid, 512);
        }
        stageN((const char*)(dsts + e0), nb + DSTOFF, 512, tid, 512);
    };

    const char* w2p0 = w2lds;
    const char* w2p1 = w2lds + 32768;
    const long e00 = (long)tb * 5 * 128;
    {
        const int pa = pair ? 1 : 0, pb = pair ? 2 : 3;
        stageN(w2bf + pa * 32768, w2lds, 32768, tid, 512);
        stageN(w2bf + pb * 32768, w2lds + 32768, 32768, tid, 512);
        stage_tile(bufs[0], e00);
    }
    __syncthreads();

    const int arow = erow + lm;

    for (int tt = 0; tt < 5; ++tt) {
        char* fb = bufs[tt & 1];
        const long e0 = e00 + (long)tt * 128;
        if (tt < 4) stage_tile(bufs[(tt & 1) ^ 1], e0 + 128);

        const bf16x8 a0 = *(const bf16x8*)(h_bf + (e0 + arow) * 128 + q * 16);
        const bf16x8 a1 = *(const bf16x8*)(h_bf + (e0 + arow) * 128 + 64 + q * 16);

        u16x8 flo[4], fhi[4];
        #pragma unroll
        for (int r = 0; r < 4; ++r) {
            const int el = erow + 4 * q + r;
            flo[r] = *(const u16x8*)(fb + el * 32);
            fhi[r] = *(const u16x8*)(fb + el * 32 + 16);
        }

        float ac0[4] = {0,0,0,0}, ac1[4] = {0,0,0,0}, ac2[4] = {0,0,0,0}, ac3[4] = {0,0,0,0};

        if (pair == 0) {   // {A, D}
            u16x8 zlo[4], zhi[4];
            #pragma unroll
            for (int r = 0; r < 4; ++r) {
                const int el = erow + 4 * q + r;
                zlo[r] = *(const u16x8*)(fb + 4096 + el * 32);
                zhi[r] = *(const u16x8*)(fb + 4096 + el * 32 + 16);
            }
            #pragma unroll
            for (int t = 0; t < 16; ++t) {
                const int rowb = (t * 16 + lm) << 7;
                const bf16x8 b00 = *(const bf16x8*)(w2p0 + rowb + s0);
                const bf16x8 b01 = *(const bf16x8*)(w2p0 + rowb + s1);
                const bf16x8 b10 = *(const bf16x8*)(w2p1 + rowb + s0);
                const bf16x8 b11 = *(const bf16x8*)(w2p1 + rowb + s1);
                f32x4 wA = {0.f,0.f,0.f,0.f}, wD = {0.f,0.f,0.f,0.f};
                wA = __builtin_amdgcn_mfma_f32_16x16x32_bf16(a0, b00, wA, 0,0,0);
                wA = __builtin_amdgcn_mfma_f32_16x16x32_bf16(a1, b01, wA, 0,0,0);
                wD = __builtin_amdgcn_mfma_f32_16x16x32_bf16(a0, b10, wD, 0,0,0);
                wD = __builtin_amdgcn_mfma_f32_16x16x32_bf16(a1, b11, wD, 0,0,0);
                #pragma unroll
                for (int r = 0; r < 4; ++r) {
                    ac0[r] += wA[r] * (t < 8 ? bfe(flo[r], t) : bfe(fhi[r], t - 8));
                    ac1[r] += wD[r] * (t < 8 ? bfe(zlo[r], t) : bfe(zhi[r], t - 8));
                }
            }
            float* summ32 = (float*)summb;
            #pragma unroll
            for (int r = 0; r < 4; ++r) {
                const int el = erow + 4 * q + r;
                summ32[lm * 132 + el] = S * (ac0[r] + 0.5773502691896258f * ac1[r]);
            }
        } else {           // {B, C}
            #pragma unroll
            for (int t = 0; t < 16; ++t) {
                const int rowb = (t * 16 + lm) << 7;
                const bf16x8 b00 = *(const bf16x8*)(w2p0 + rowb + s0);
                const bf16x8 b01 = *(const bf16x8*)(w2p0 + rowb + s1);
                const bf16x8 b10 = *(const bf16x8*)(w2p1 + rowb + s0);
                const bf16x8 b11 = *(const bf16x8*)(w2p1 + rowb + s1);
                f32x4 wB = {0.f,0.f,0.f,0.f}, wC = {0.f,0.f,0.f,0.f};
                wB = __builtin_amdgcn_mfma_f32_16x16x32_bf16(a0, b00, wB, 0,0,0);
                wB = __builtin_amdgcn_mfma_f32_16x16x32_bf16(a1, b01, wB, 0,0,0);
                wC = __builtin_amdgcn_mfma_f32_16x16x32_bf16(a0, b10, wC, 0,0,0);
                wC = __builtin_amdgcn_mfma_f32_16x16x32_bf16(a1, b11, wC, 0,0,0);
                #pragma unroll
                for (int r = 0; r < 4; ++r) {
                    const int el = erow + 4 * q + r;
                    const uint2 xv = *(const uint2*)(fb + 4096 + ((t << 7) + el) * 8);
                    ac0[r] += wB[r] * (t < 8 ? bfe(flo[r], t) : bfe(fhi[r], t - 8));
                    ac1[r] += wC[r] * bflo(xv.x);
                    ac2[r] += wC[r] * bfhi(xv.x);
                    ac3[r] += wC[r] * bflo(xv.y);
                }
            }
            unsigned short* summ16 = (unsigned short*)summb;
            #pragma unroll
            for (int r = 0; r < 4; ++r) {
                const int el = erow + 4 * q + r;
                const float4 y = *(const float4*)(fb + 20736 + el * 16);
                const float b = S * ac0[r];
                summ16[(3 * lm + 0) * 132 + el] = (unsigned short)f2bf(b * y.x + S * ac1[r]);
                summ16[(3 * lm + 1) * 132 + el] = (unsigned short)f2bf(b * y.y + S * ac2[r]);
                summ16[(3 * lm + 2) * 132 + el] = (unsigned short)f2bf(b * y.z + S * ac3[r]);
            }
        }
        const int* dstl = (const int*)(fb + DSTOFF);
        if (wv < 2) {   // segment boundaries per 64-edge half
            const int base = wv << 6;
            const int d = dstl[base + lane];
            const bool flag = (lane == 0) || (d != dstl[base + lane - 1]);
            const unsigned long long m = __ballot(flag);
            const int sid = (lane == 0) ? 0 : __popcll(m & ((1ull << lane) - 1ull));
            if (flag) segst[wv][sid] = base + lane;
            if (lane == 63) { const int ns = __popcll(m); nseg[wv] = ns; segst[wv][ns] = base + 64; }
        }
        __syncthreads();  // B1: summand/segments visible; staged loads drained
        const int nsa = nseg[0], nsb = nseg[1];
        if (pair == 0) {
            const float* sm = (const float*)summb;
            const int total = (nsa + nsb) << 4;
            for (int i = tid; i < total; i += 512) {
                const int sg = i >> 4, c = i & 15;
                const int hh = (sg >= nsa) ? 1 : 0;
                const int sl = hh ? sg - nsa : sg;
                const int eb = segst[hh][sl], ee = segst[hh][sl + 1];
                float s = 0.f;
                for (int e = eb; e < ee; ++e) s += sm[c * 132 + e];
                atomicAdd(&out[(size_t)dstl[eb] * 64 + c], s);
            }
        } else {
            const unsigned short* sm = (const unsigned short*)summb;
            const int total = (nsa + nsb) * 48;
            for (int i = tid; i < total; i += 512) {
                const int sg = i / 48, c = i - sg * 48;
                const int hh = (sg >= nsa) ? 1 : 0;
                const int sl = hh ? sg - nsa : sg;
                const int eb = segst[hh][sl], ee = segst[hh][sl + 1];
                float s = 0.f;
                for (int e = eb; e < ee; ++e) s += bf2f(sm[c * 132 + e]);
                atomicAdd(&out[(size_t)dstl[eb] * 64 + 16 + c], s);
            }
        }
        __syncthreads();  // B2: reduce done
    }
}

// ---------------- fallback (round-2 path, small-ws) ----------------
#define FBT 64
template<int PATH>
__device__ __forceinline__ void fb_body(
    const float* __restrict__ x, const float* __restrict__ edge_vec,
    const float* __restrict__ w1, const float* __restrict__ w2,
    const int* __restrict__ src, const int* __restrict__ perm,
    const int* __restrict__ dsts, float* __restrict__ out,
    unsigned short (*w2t)[72], float* arena, float (*y1l)[4],
    int* dstl, int* srcl, int* segstart, int* nseg_s)
{
    constexpr int NC    = (PATH == 0 || PATH == 3) ? 16 : 48;
    constexpr int CBASE = (PATH == 0 || PATH == 3) ? 0 : 16;
    const int tid = threadIdx.x;
    float* embl = arena;
    unsigned short* hl = (unsigned short*)(arena + 640);
    float* feats = arena + 2944;
    float* summ  = arena;
    {
        const float* col = w2 + PATH * 256 + tid;
        #pragma unroll
        for (int k = 0; k < 64; k += 2) {
            const unsigned int lo = f2bf(col[(size_t)k * 1024]);
            const unsigned int hi = f2bf(col[(size_t)(k + 1) * 1024]);
            *(unsigned int*)&w2t[tid][k] = lo | (hi << 16);
        }
    }
    const int lane = tid & 63, wv = tid >> 6, lm = lane & 15, q = lane >> 4;
    const int erow = wv * 16;
    const float C0 = 1.14136f * __expf(2.0f) * 3.1622776601683795f;
    const float S  = 0.17677669529663687f * 0.125f * 0.0625f;
    for (int it = 0; it < 2; ++it) {
        const int e0 = (blockIdx.x * 2 + it) * FBT;
        __syncthreads();
        for (int idx = tid; idx < FBT * 10; idx += 256) {
            const int e = idx / 10, i = idx - e * 10;
            const int eid = perm[e0 + e];
            const float vx = edge_vec[eid * 3 + 0], vy = edge_vec[eid * 3 + 1], vz = edge_vec[eid * 3 + 2];
            const float r = sqrtf(vx * vx + vy * vy + vz * vz);
            const float diff = r * (11.0f / 4.5f) - (float)(i + 1);
            embl[e * 10 + i] = C0 * sus_f(diff + 1.0f) * sus_f(1.0f - diff);
            if (i == 0) {
                const float sc = 1.7320508075688772f / r;
                y1l[e][0] = vx * sc; y1l[e][1] = vy * sc; y1l[e][2] = vz * sc;
                dstl[e] = dsts[e0 + e];
                srcl[e] = src[eid];
            }
        }
        __syncthreads();
        for (int idx = tid; idx < FBT * 8; idx += 256) {
            const int e = idx >> 3, j0 = (idx & 7) * 8;
            float acc[8];
            #pragma unroll
            for (int j = 0; j < 8; ++j) acc[j] = 0.0f;
            #pragma unroll
            for (int i = 0; i < 10; ++i) {
                const float ei = embl[e * 10 + i];
                #pragma unroll
                for (int j = 0; j < 8; ++j) acc[j] += ei * w1[i * 64 + j0 + j];
            }
            unsigned int pk[4];
            #pragma unroll
            for (int p = 0; p < 4; ++p) {
                const unsigned int lo = f2bf(fmaxf(acc[2 * p],     0.0f) * 0.4472135954999579f);
                const unsigned int hi = f2bf(fmaxf(acc[2 * p + 1], 0.0f) * 0.4472135954999579f);
                pk[p] = lo | (hi << 16);
            }
            uint4 v; v.x = pk[0]; v.y = pk[1]; v.z = pk[2]; v.w = pk[3];
            *(uint4*)&hl[e * 72 + j0] = v;
        }
        if (PATH == 2) {
            for (int idx = tid; idx < FBT * 48; idx += 256) {
                const int e = idx / 48, c = idx - e * 48;
                feats[e * 48 + c] = x[(size_t)srcl[e] * 64 + 16 + c];
            }
        } else if (PATH == 3) {
            for (int idx = tid; idx < FBT * 16; idx += 256) {
                const int e = idx >> 4, u = idx & 15;
                const float* xs = x + (size_t)srcl[e] * 64 + 16 + u * 3;
                feats[e * 16 + u] = xs[0] * y1l[e][0] + xs[1] * y1l[e][1] + xs[2] * y1l[e][2];
            }
        } else {
            for (int idx = tid; idx < FBT * 16; idx += 256) {
                const int e = idx >> 4, u = idx & 15;
                feats[e * 16 + u] = x[(size_t)srcl[e] * 64 + u];
            }
        }
        __syncthreads();
        const bf16x8 a0 = *(const bf16x8*)&hl[(erow + lm) * 72 + 8 * q];
        const bf16x8 a1 = *(const bf16x8*)&hl[(erow + lm) * 72 + 32 + 8 * q];
        float accO[4] = {0.f,0.f,0.f,0.f}, accC0[4] = {0.f,0.f,0.f,0.f};
        float accC1[4] = {0.f,0.f,0.f,0.f}, accC2[4] = {0.f,0.f,0.f,0.f};
        #pragma unroll 4
        for (int t = 0; t < 16; ++t) {
            const bf16x8 b0 = *(const bf16x8*)&w2t[t * 16 + lm][8 * q];
            const bf16x8 b1 = *(const bf16x8*)&w2t[t * 16 + lm][32 + 8 * q];
            f32x4 wa = {0.f,0.f,0.f,0.f};
            wa = __builtin_amdgcn_mfma_f32_16x16x32_bf16(a0, b0, wa, 0, 0, 0);
            wa = __builtin_amdgcn_mfma_f32_16x16x32_bf16(a1, b1, wa, 0, 0, 0);
            #pragma unroll
            for (int r = 0; r < 4; ++r) {
                const int el = erow + 4 * q + r;
                if (PATH == 2) {
                    accC0[r] += wa[r] * feats[el * 48 + t * 3 + 0];
                    accC1[r] += wa[r] * feats[el * 48 + t * 3 + 1];
                    accC2[r] += wa[r] * feats[el * 48 + t * 3 + 2];
                } else {
                    accO[r] += wa[r] * feats[el * 16 + t];
                }
            }
        }
        __syncthreads();
        #pragma unroll
        for (int r = 0; r < 4; ++r) {
            const int el = erow + 4 * q + r;
            if (PATH == 0) summ[el * 16 + lm] = S * accO[r];
            else if (PATH == 3) summ[el * 16 + lm] = S * 0.5773502691896258f * accO[r];
            else if (PATH == 1) {
                const float tv = S * accO[r];
                summ[el * 48 + lm * 3 + 0] = tv * y1l[el][0];
                summ[el * 48 + lm * 3 + 1] = tv * y1l[el][1];
                summ[el * 48 + lm * 3 + 2] = tv * y1l[el][2];
            } else {
                summ[el * 48 + lm * 3 + 0] = S * accC0[r];
                summ[el * 48 + lm * 3 + 1] = S * accC1[r];
                summ[el * 48 + lm * 3 + 2] = S * accC2[r];
            }
        }
        if (tid < 64) {
            const int d = dstl[tid];
            const bool flag = (tid == 0) || (d != dstl[tid - 1]);
            const unsigned long long m = __ballot(flag);
            const int sid = (tid == 0) ? 0 : __popcll(m & ((1ull << tid) - 1ull));
            if (flag) segstart[sid] = tid;
            if (tid == 63) { const int ns = __popcll(m); *nseg_s = ns; segstart[ns] = 64; }
        }
        __syncthreads();
        const int ns = *nseg_s;
        for (int i = tid; i < ns * NC; i += 256) {
            const int s = i / NC, c = i - s * NC;
            const int eb = segstart[s], ee = segstart[s + 1];
            float sum = 0.0f;
            for (int e = eb; e < ee; ++e) sum += summ[e * NC + c];
            atomicAdd(&out[(size_t)dstl[eb] * 64 + CBASE + c], sum);
        }
    }
}

__global__ __launch_bounds__(256, 2) void fb_edge(
    const float* __restrict__ x, const float* __restrict__ edge_vec,
    const float* __restrict__ w1, const float* __restrict__ w2,
    const int* __restrict__ src, const int* __restrict__ perm,
    const int* __restrict__ dsts, float* __restrict__ out)
{
    __shared__ unsigned short w2t[256][72];
    __shared__ float arena[6016];
    __shared__ float y1l[FBT][4];
    __shared__ int dstl[FBT];
    __shared__ int srcl[FBT];
    __shared__ int segstart[FBT + 1];
    __shared__ int nseg_s;
    switch (blockIdx.y) {
        case 0:  fb_body<0>(x, edge_vec, w1, w2, src, perm, dsts, out, w2t, arena, y1l, dstl, srcl, segstart, &nseg_s); break;
        case 1:  fb_body<1>(x, edge_vec, w1, w2, src, perm, dsts, out, w2t, arena, y1l, dstl, srcl, segstart, &nseg_s); break;
        case 2:  fb_body<2>(x, edge_vec, w1, w2, src, perm, dsts, out, w2t, arena, y1l, dstl, srcl, segstart, &nseg_s); break;
        default: fb_body<3>(x, edge_vec, w1, w2, src, perm, dsts, out, w2t, arena, y1l, dstl, srcl, segstart, &nseg_s); break;
    }
}

// ---------------- host ----------------
extern "C" void kernel_launch(void* const* d_in, const int* in_sizes, int n_in,
                              void* d_out, int out_size, void* d_ws, size_t ws_size,
                              hipStream_t stream) {
    const float* x        = (const float*)d_in[0];
    const float* edge_vec = (const float*)d_in[1];
    const float* w1       = (const float*)d_in[2];
    const float* w2       = (const float*)d_in[3];
    const int*   src      = (const int*)d_in[4];
    const int*   dst      = (const int*)d_in[5];
    float* out = (float*)d_out;

    char* ws = (char*)d_ws;
    size_t off = 0;
    auto alloc = [&](size_t n) -> char* {
        off = (off + 255) & ~(size_t)255;
        char* p = ws + off; off += n; return p;
    };
    int* hist    = (int*)alloc(40000);
    int* cursor  = (int*)alloc(40000);
    int* offsets = (int*)alloc(40004);
    int* perm    = (int*)alloc(640000);
    int* dsts    = (int*)alloc(640000);
    char* w2bf   = alloc(131072);
    char* h_bf   = alloc((size_t)NE * 128);
    char* X0g    = alloc((size_t)NE * 32);
    char* Zg     = alloc((size_t)NE * 32);
    char* X1g    = alloc((size_t)NE * 128);
    float* Y1g   = (float*)alloc((size_t)NE * 16);
    const bool big = (off <= ws_size);

    hipMemsetAsync(d_out, 0, (size_t)out_size * sizeof(float), stream);
    hipMemsetAsync(d_ws, 0, 81408, stream);  // hist + cursor

    if (big) {
        hipLaunchKernelGGL(hist_k, dim3(657), dim3(256), 0, stream, dst, hist, w2, w2bf);
        hipLaunchKernelGGL(scan_k, dim3(1), dim3(1024), 0, stream, hist, offsets);
        hipLaunchKernelGGL(scatter_k, dim3(625), dim3(256), 0, stream, dst, offsets, cursor, perm, dsts);
        hipLaunchKernelGGL(prep_k, dim3(1250), dim3(256), 0, stream,
                           x, edge_vec, w1, src, perm, h_bf, X0g, Zg, X1g, Y1g);
        hipLaunchKernelGGL(se3_edge, dim3(250, 2), dim3(512), 0, stream,
                           w2bf, h_bf, X0g, Zg, X1g, Y1g, dsts, out);
    } else {
        hipLaunchKernelGGL(hist_k, dim3(625), dim3(256), 0, stream, dst, hist, w2, w2bf);
        hipLaunchKernelGGL(scan_k, dim3(1), dim3(1024), 0, stream, hist, offsets);
        hipLaunchKernelGGL(scatter_k, dim3(625), dim3(256), 0, stream, dst, offsets, cursor, perm, dsts);
        hipLaunchKernelGGL(fb_edge, dim3(1250, 4), dim3(256), 0, stream,
                           x, edge_vec, w1, w2, src, perm, dsts, out);
    }
}